// Round 12
// baseline (169.167 us; speedup 1.0000x reference)
//
#include <hip/hip_runtime.h>
#include <hip/hip_bf16.h>

#define BB 8
#define NN 128
#define DD 128

typedef __attribute__((ext_vector_type(8))) short bf16x8;
typedef __attribute__((ext_vector_type(4))) float floatx4;

__device__ __forceinline__ unsigned short f2bf(float f) {
    unsigned int bits = __float_as_uint(f);
    unsigned int r = bits + 0x7FFFu + ((bits >> 16) & 1u);
    return (unsigned short)(r >> 16);
}

// ws layout (float units)
#define WS_X0F   0         // 131072 f  fp32 x ping
#define WS_X1F   131072    // 131072 f  fp32 x pong
#define WS_W1T   262144    // 34816 ushorts: w1t[n][d] = W1[n&127][(n>>7)*128+d], stride 136
#define WS_W2B   279552    // 17408 ushorts: w2b[e][d] = W2[e][d], stride 136
// total 288256 floats = 1.15 MB

// ---------------- K_init: embed gather (fp32) + bf16 weight images ----------------
__global__ __launch_bounds__(256) void k_init(const int* __restrict__ tok,
                                              const float* __restrict__ embf,
                                              const float* __restrict__ W1f,
                                              const float* __restrict__ W2f,
                                              float* __restrict__ ws) {
    float* x0f = ws + WS_X0F;
    unsigned short* gw1t = (unsigned short*)(ws + WS_W1T);
    unsigned short* gw2b = (unsigned short*)(ws + WS_W2B);
    int blk = blockIdx.x, t = threadIdx.x;
    if (blk < 32) {                       // x0f = embed[tok]  (fp32)
        int base = blk * 4096;
#pragma unroll
        for (int it = 0; it < 16; ++it) {
            int idx = base + it * 256 + t;
            int r = idx >> 7, d = idx & 127;
            x0f[idx] = embf[tok[r] * DD + d];
        }
    } else if (blk < 41) {                // w1t (256x136): B[n][d] = W1[n&127][(n>>7)*128+d]
        int base = (blk - 32) * 4096;
#pragma unroll
        for (int it = 0; it < 16; ++it) {
            int idx = base + it * 256 + t;
            if (idx < 256 * 136) {
                int e = idx / 136, d = idx - e * 136;
                gw1t[idx] = (d < 128) ? f2bf(W1f[(e & 127) * 256 + (e >> 7) * 128 + d])
                                      : (unsigned short)0;
            }
        }
    } else {                              // w2b (128x136): W2[e][d]   (blk 41..45)
        int base = (blk - 41) * 4096;
#pragma unroll
        for (int it = 0; it < 16; ++it) {
            int idx = base + it * 256 + t;
            if (idx < 128 * 136) {
                int e = idx / 136, d = idx - e * 136;
                gw2b[idx] = (d < 128) ? f2bf(W2f[e * 128 + d]) : (unsigned short)0;
            }
        }
    }
}

// ---------------- K_round: ONE GNN round (round-7 compute verbatim, no barrier) ----------
// 256 blocks x 512 threads; block (b,g) owns rows i0=4g..4g+3.
// Round ordering comes from dispatch boundaries; x travels fp32 through ws.
__global__ __launch_bounds__(512, 2) void k_round(const float* __restrict__ Af,
                                                  const float* __restrict__ b1f,
                                                  const float* __restrict__ b2f,
                                                  const float* __restrict__ curf,
                                                  float* __restrict__ nxtf,
                                                  const unsigned short* __restrict__ gw1t,
                                                  const unsigned short* __restrict__ gw2b) {
    __shared__ __align__(16) unsigned short w1t[256 * 136];   // 69632 B
    __shared__ __align__(16) unsigned short w2b[128 * 136];   // 34816 B
    __shared__ __align__(16) unsigned short xb[128 * 136];    // 34816 B; Xb then Hjb
    __shared__ __align__(16) float red[4][4][128];            // 8192 B
    __shared__ float a_s[4][128];                             // 2048 B
    __shared__ __align__(16) float hja_s[4][128];             // 2048 B
    __shared__ float b1s[128], b2s[128];                      // 1024 B  (total ~153 KB)

    int blk = blockIdx.x;
    int b = blk >> 5, g = blk & 31, i0 = g * 4;
    int t = threadIdx.x;
    int wave = t >> 6, lane = t & 63;
    int col = lane & 15, quad = lane >> 4;

    // ---- stage weights (hot L2) ----
    {
        const uint4* s1 = (const uint4*)gw1t; uint4* d1 = (uint4*)w1t;
#pragma unroll
        for (int it = 0; it < 9; ++it) { int idx = it * 512 + t; if (idx < 4352) d1[idx] = s1[idx]; }
        const uint4* s2 = (const uint4*)gw2b; uint4* d2 = (uint4*)w2b;
#pragma unroll
        for (int it = 0; it < 5; ++it) { int idx = it * 512 + t; if (idx < 2176) d2[idx] = s2[idx]; }
    }
    if (t < 128) { b1s[t] = b1f[t]; b2s[t] = b2f[t]; }
    a_s[t >> 7][t & 127] = Af[(b * NN + (t & 127)) * NN + i0 + (t >> 7)];  // A[b, j, i0+ii]

    // owned x element (fp32)
    float xown = curf[(b * NN + i0 + (t >> 7)) * DD + (t & 127)];

    const int myw = i0 >> 4;
    const int qr  = g & 3;

    // ---- stage Xb: fp32 -> bf16 convert (round-7 pattern, plain loads) ----
    const float* curb = curf + b * NN * DD;
#pragma unroll
    for (int it = 0; it < 16; ++it) {
        int idx = it * 1024 + t * 2;
        int j = idx >> 7, d = idx & 127;
        float2 v = *reinterpret_cast<const float2*>(curb + j * DD + d);
        unsigned int packed = (unsigned int)f2bf(v.x) | ((unsigned int)f2bf(v.y) << 16);
        *reinterpret_cast<unsigned int*>(&xb[j * 136 + d]) = packed;
    }
    __syncthreads();

    // ---- GEMM1: proj = Xb @ W1^T (m=j: wave's 16 rows; n=0..255) ----  [round-7 verbatim]
    bf16x8 af[4];
#pragma unroll
    for (int ks = 0; ks < 4; ++ks)
        af[ks] = *reinterpret_cast<const bf16x8*>(&xb[(wave * 16 + col) * 136 + ks * 32 + quad * 8]);
    floatx4 acc1[16];
#pragma unroll
    for (int nt = 0; nt < 16; ++nt) acc1[nt] = (floatx4){0.f, 0.f, 0.f, 0.f};
#pragma unroll
    for (int nt = 0; nt < 16; ++nt)
#pragma unroll
        for (int ks = 0; ks < 4; ++ks) {
            bf16x8 bfc = *reinterpret_cast<const bf16x8*>(&w1t[(nt * 16 + col) * 136 + ks * 32 + quad * 8]);
            acc1[nt] = __builtin_amdgcn_mfma_f32_16x16x32_bf16(af[ks], bfc, acc1[nt], 0, 0, 0);
        }
    // hja capture (C layout: col=lane&15, row=quad*4+reg)
    if (wave == myw && quad == qr) {
#pragma unroll
        for (int nt = 0; nt < 8; ++nt) {
            int d = nt * 16 + col;
#pragma unroll
            for (int rr = 0; rr < 4; ++rr) hja_s[rr][d] = acc1[nt][rr];
        }
    }
    // Hjb (+b1) bf16 into xb region (own rows only -> no cross-wave WAR)
#pragma unroll
    for (int nt = 8; nt < 16; ++nt) {
        int d = (nt - 8) * 16 + col;
#pragma unroll
        for (int rr = 0; rr < 4; ++rr) {
            int j = wave * 16 + quad * 4 + rr;
            xb[j * 136 + d] = f2bf(acc1[nt][rr] + b1s[d]);
        }
    }
    __syncthreads();

    // ---- GEMM2 per owned row i ----  [round-7 verbatim]
    int we = wave & 1, wj = wave >> 1;
    int ebase = we * 64, jbase = wj * 32;
    bf16x8 bw[4][4];
#pragma unroll
    for (int et = 0; et < 4; ++et)
#pragma unroll
        for (int ks = 0; ks < 4; ++ks)
            bw[et][ks] = *reinterpret_cast<const bf16x8*>(&w2b[(ebase + et * 16 + col) * 136 + ks * 32 + quad * 8]);
#pragma unroll
    for (int ii = 0; ii < 4; ++ii) {
        floatx4 acc2[2][4];
#pragma unroll
        for (int jt = 0; jt < 2; ++jt)
#pragma unroll
            for (int et = 0; et < 4; ++et) acc2[jt][et] = (floatx4){0.f, 0.f, 0.f, 0.f};
#pragma unroll
        for (int jt = 0; jt < 2; ++jt)
#pragma unroll
            for (int ks = 0; ks < 4; ++ks) {
                int k0 = ks * 32 + quad * 8;
                union { bf16x8 v; unsigned int u[4]; } Rw, Ho;
                Rw.v = *reinterpret_cast<const bf16x8*>(&xb[(jbase + jt * 16 + col) * 136 + k0]);
                const float* hb = &hja_s[ii][k0];
#pragma unroll
                for (int p = 0; p < 4; ++p) {   // H = relu(hja_i + Hjb) in-register
                    float f0 = __uint_as_float(Rw.u[p] << 16);
                    float f1 = __uint_as_float(Rw.u[p] & 0xFFFF0000u);
                    f0 = fmaxf(f0 + hb[2 * p], 0.f);
                    f1 = fmaxf(f1 + hb[2 * p + 1], 0.f);
                    Ho.u[p] = (unsigned int)f2bf(f0) | ((unsigned int)f2bf(f1) << 16);
                }
#pragma unroll
                for (int et = 0; et < 4; ++et)
                    acc2[jt][et] = __builtin_amdgcn_mfma_f32_16x16x32_bf16(Ho.v, bw[et][ks], acc2[jt][et], 0, 0, 0);
            }
#pragma unroll
        for (int et = 0; et < 4; ++et) {
            int e = ebase + et * 16 + col;
            float be = b2s[e];
            float s = 0.f;
#pragma unroll
            for (int jt = 0; jt < 2; ++jt) {
                int j0 = jbase + jt * 16 + quad * 4;
#pragma unroll
                for (int rr = 0; rr < 4; ++rr)
                    s += a_s[ii][j0 + rr] * fmaxf(acc2[jt][et][rr] + be, 0.f);
            }
            s += __shfl_xor(s, 16, 64);
            s += __shfl_xor(s, 32, 64);
            if (quad == 0) red[wj][ii][e] = s;
        }
    }
    __syncthreads();

    // ---- finalize: x_nxt = x_cur + msg (plain fp32 store) ----
    {
        int ii = t >> 7, e = t & 127;
        xown += red[0][ii][e] + red[1][ii][e] + red[2][ii][e] + red[3][ii][e];
        nxtf[(b * NN + i0 + ii) * DD + e] = xown;
    }
}

// ---------------- K_head: head for all 1024 rows (round-4 verbatim) ----------------
__global__ __launch_bounds__(128) void k_head(const float* __restrict__ x,
                                              const float* __restrict__ Wo1f,
                                              const float* __restrict__ bo1f,
                                              const float* __restrict__ Wo2f,
                                              float* __restrict__ out) {
    __shared__ __align__(16) float zs[DD];
    __shared__ float rs[DD];
    int r = blockIdx.x;
    int t = threadIdx.x;
    zs[t] = x[r * DD + t];
    __syncthreads();
    const float4* wrow = reinterpret_cast<const float4*>(Wo1f + t * DD);
    float acc = 0.f;
#pragma unroll
    for (int d4 = 0; d4 < 32; ++d4) {
        float4 w = wrow[d4];
        acc += zs[d4 * 4 + 0] * w.x + zs[d4 * 4 + 1] * w.y
             + zs[d4 * 4 + 2] * w.z + zs[d4 * 4 + 3] * w.w;
    }
    rs[t] = fmaxf(acc + bo1f[t], 0.f);
    __syncthreads();
    if (t < 10) {
        const float* w2r = Wo2f + t * DD;
        float s = 0.f;
#pragma unroll
        for (int e2 = 0; e2 < DD; ++e2) s += rs[e2] * w2r[e2];
        int bb = r >> 7, nn = r & 127;
        out[80 + r * 10 + t] = s;            // x_all (8,128,10) after out (8,10)
        if (nn == 0) out[bb * 10 + t] = s;   // out == x_all[:,0,:]
    }
}

extern "C" void kernel_launch(void* const* d_in, const int* in_sizes, int n_in,
                              void* d_out, int out_size, void* d_ws, size_t ws_size,
                              hipStream_t stream) {
    const int*   tok  = (const int*)d_in[0];
    const float* Af   = (const float*)d_in[1];
    const float* embf = (const float*)d_in[2];
    const float* W1f  = (const float*)d_in[3];
    const float* b1f  = (const float*)d_in[4];
    const float* W2f  = (const float*)d_in[5];
    const float* b2f  = (const float*)d_in[6];
    const float* Wo1f = (const float*)d_in[7];
    const float* bo1f = (const float*)d_in[8];
    const float* Wo2f = (const float*)d_in[9];

    float* ws  = (float*)d_ws;
    float* out = (float*)d_out;
    float* x0f = ws + WS_X0F;
    float* x1f = ws + WS_X1F;
    const unsigned short* gw1t = (const unsigned short*)(ws + WS_W1T);
    const unsigned short* gw2b = (const unsigned short*)(ws + WS_W2B);

    k_init<<<46, 256, 0, stream>>>(tok, embf, W1f, W2f, ws);
    for (int r = 0; r < 5; ++r) {
        const float* cf = (r & 1) ? x1f : x0f;
        float*       nf = (r & 1) ? x0f : x1f;
        k_round<<<256, 512, 0, stream>>>(Af, b1f, b2f, cf, nf, gw1t, gw2b);
    }
    k_head<<<BB * NN, 128, 0, stream>>>(x1f, Wo1f, bo1f, Wo2f, out);
}